// Round 6
// baseline (589.098 us; speedup 1.0000x reference)
//
#include <hip/hip_runtime.h>

#define K_CB   8192
#define D_DIM  256
#define N_ROWS 32768
#define Q_ELEMS (N_ROWS * D_DIM)

#define M_FLAG 1.3e-4f   // np-window 6.1e-5 + bf16 score noise + 13-bit pack + wsq-omission (3e-9)
#define M_CAND 1.3e-4f
#define CAP    16

typedef __bf16 bf16x8 __attribute__((ext_vector_type(8)));
typedef float  f32x16 __attribute__((ext_vector_type(16)));

// async 16B global->LDS DMA: LDS dest is WAVE-UNIFORM base; HW adds lane*16.
#define ASYNC_COPY16(gp, lp)                                              \
    __builtin_amdgcn_global_load_lds(                                     \
        (const __attribute__((address_space(1))) unsigned int*)(gp),      \
        (__attribute__((address_space(3))) unsigned int*)(lp), 16, 0, 0)

// ws layout (bytes):
//   0        Wsq        [8192 f32]   (rescore only now)
//   32768    Xsq        [32768 f32]  (slot kept)
//   163840   Rmin       [32768 f32]  (packed b1, NO wsq: low 13 mantissa bits = k)
//   294912   accum f32 | 294916 flag_count u32 | 294920 hard_count u32  (memset 12B)
//   294924   flags      [32768 i32]
//   425996   hard_flags [32768 i32]
//   557068   candcnt    [32768 i32]
//   688140   cands      [32768*16 i32]
//   2785296  Wbf        [8192*256 ushort] = bf16(-2w), 32-COL-GROUP slice-major:
//            byte(k,s) = (k>>5)*16384 + s*512 + (k&31)*16   (s = d/8, 8 bf16 per 16B)
//            -> 128-col tile T = bytes [T*65536,+65536) contiguous; identity DMA;
//               ds_read_b128 = 32 consecutive 16B per half-wave, conflict-free.

__device__ inline ushort f2bf(float f) {          // RNE float->bf16
    unsigned u = __float_as_uint(f);
    unsigned r = u + 0x7FFFu + ((u >> 16) & 1u);
    return (ushort)(r >> 16);
}

__device__ inline uint4 pack8(float4 a, float4 b) {
    uint4 o;
    o.x = (unsigned)f2bf(a.x) | ((unsigned)f2bf(a.y) << 16);
    o.y = (unsigned)f2bf(a.z) | ((unsigned)f2bf(a.w) << 16);
    o.z = (unsigned)f2bf(b.x) | ((unsigned)f2bf(b.y) << 16);
    o.w = (unsigned)f2bf(b.z) | ((unsigned)f2bf(b.w) << 16);
    return o;
}

// fused: np-exact w_sq (fp64 sum -> fp32, EXACT old shuffle-tree order) +
// Wbf = bf16(-2w) in 32-col-group slice-major layout.
__global__ __launch_bounds__(256) void wsq_wbf_kernel(const float* __restrict__ w,
                                                      float* __restrict__ wsq,
                                                      ushort* __restrict__ wbf) {
    __shared__ __align__(16) ushort tile[64 * 256];   // 32KB: two 16KB 32-col groups
    const int t = threadIdx.x;
    const int kb = blockIdx.x;                        // 128 blocks of 64 codewords
    const int wv = t >> 6, lane = t & 63;

    const float4* wb = reinterpret_cast<const float4*>(w) + (size_t)kb * 4096;
    #pragma unroll
    for (int i = 0; i < 16; ++i) {
        int j = i * 256 + t;                          // float4 idx: c = j>>6, d4 = j&63
        float4 v = wb[j];
        int c = j >> 6, d4 = j & 63;
        uint2 o;
        o.x = (unsigned)f2bf(-2.0f * v.x) | ((unsigned)f2bf(-2.0f * v.y) << 16);
        o.y = (unsigned)f2bf(-2.0f * v.z) | ((unsigned)f2bf(-2.0f * v.w) << 16);
        *reinterpret_cast<uint2*>((char*)tile + (size_t)(c >> 5) * 16384
                                  + (size_t)(d4 >> 1) * 512 + (c & 31) * 16 + (d4 & 1) * 8) = o;
    }

    for (int c = wv; c < 64; c += 4) {
        float4 v = reinterpret_cast<const float4*>(w)[(size_t)(kb * 64 + c) * 64 + lane];
        double sq = (double)v.x * v.x + (double)v.y * v.y + (double)v.z * v.z + (double)v.w * v.w;
        #pragma unroll
        for (int off = 32; off > 0; off >>= 1) sq += __shfl_down(sq, off, 64);
        if (lane == 0) wsq[kb * 64 + c] = (float)sq;
    }

    __syncthreads();
    const uint4* src = reinterpret_cast<const uint4*>(tile);
    uint4* dst = reinterpret_cast<uint4*>((char*)wbf + (size_t)kb * 32768);
    #pragma unroll
    for (int j = 0; j < 8; ++j) dst[j * 256 + t] = src[j * 256 + t];
}

// Pass 1 (R6): pipelined epilogue + lean 3-op score tracking, NO wsq in loop.
// 128 rows/block, 8 waves = 2 rg x 4 cg, 128-col tiles, 64 iters, dbuf 2x64KB.
// Tile t's MFMAs (pA or pB) interleave with tile t-1's epilogue (the other pair):
// independent streams -> VALU fills MFMA latency instead of serializing after it.
__global__ __launch_bounds__(512, 2) void pass1_kernel(
        const float* __restrict__ x, const ushort* __restrict__ wbf,
        float* __restrict__ idx_out,
        float* __restrict__ rowmin, int* __restrict__ flags,
        unsigned* __restrict__ flag_count, int* __restrict__ hard_flags,
        unsigned* __restrict__ hard_count, int* __restrict__ candcnt,
        int* __restrict__ cands) {
    __shared__ __align__(16) char smem[132096];       // 2x64KB staging / 2x[128][129] f32

    const int t = threadIdx.x;
    const int lane = t & 63, ln31 = lane & 31, h = lane >> 5;
    const int wv = t >> 6;                            // 0..7
    const int rg = wv >> 2;                           // 0..1 (64-row group)
    const int cg = wv & 3;                            // 0..3 (32-col group)
    const int colL = cg * 32 + ln31;                  // 0..127 in tile
    const int r0 = blockIdx.x * 128;

    const char* gW = (const char*)wbf + (size_t)wv * 8192 + (size_t)lane * 16;

    // A fragments: TWO 32-row chains -> registers/AGPRs (verified R3 mapping)
    const int arow0 = r0 + rg * 64 + ln31;
    const float4* xr0 = reinterpret_cast<const float4*>(x) + (size_t)arow0 * 64;
    const float4* xr1 = xr0 + (size_t)32 * 64;
    bf16x8 afr0[16], afr1[16];
    #pragma unroll
    for (int kk = 0; kk < 16; ++kk) {
        afr0[kk] = __builtin_bit_cast(bf16x8, pack8(xr0[kk * 4 + h * 2], xr0[kk * 4 + h * 2 + 1]));
        afr1[kk] = __builtin_bit_cast(bf16x8, pack8(xr1[kk * 4 + h * 2], xr1[kk * 4 + h * 2 + 1]));
    }

    // stage tile 0 into buf0
    #pragma unroll
    for (int i = 0; i < 8; ++i) ASYNC_COPY16(gW + i * 1024, smem + wv * 8192 + i * 1024);

    float b1a[16], b2a[16], b1b[16], b2b[16];
    f32x16 pA0, pA1, pB0, pB1;
    #pragma unroll
    for (int r = 0; r < 16; ++r) {
        b1a[r] = 3.4e38f; b2a[r] = 3.4e38f; b1b[r] = 3.4e38f; b2b[r] = 3.4e38f;
        pA0[r] = 0.0f; pA1[r] = 0.0f;                 // write-accs for tile 0
        pB0[r] = 3.4e38f; pB1[r] = 3.4e38f;           // dummy "tile -1" (never wins)
    }

    for (int tt = 0; tt < 64; tt += 2) {
        // ---------- even tile tt: read buf0, stage tt+1 -> buf1; MFMA->pA, epi pB ----------
        __builtin_amdgcn_s_barrier();                 // all waves done reading buf1 (tile tt-1)
        {
            const char* g_ = gW + (size_t)((tt + 1) & 63) * 65536;
            #pragma unroll
            for (int i = 0; i < 8; ++i)
                ASYNC_COPY16(g_ + i * 1024, smem + 65536 + wv * 8192 + i * 1024);
        }
        asm volatile("s_waitcnt vmcnt(8)" ::: "memory");   // tile tt landed; tt+1 in flight
        __builtin_amdgcn_s_barrier();
        __builtin_amdgcn_sched_barrier(0);
        {
            __builtin_amdgcn_s_setprio(1);
            #pragma unroll
            for (int kk = 0; kk < 16; ++kk) {         // 1 B-read feeds 2 MFMAs
                bf16x8 bf = *reinterpret_cast<const bf16x8*>(
                    smem + cg * 16384 + (kk * 2 + h) * 512 + ln31 * 16);
                pA0 = __builtin_amdgcn_mfma_f32_32x32x16_bf16(afr0[kk], bf, pA0, 0, 0, 0);
                pA1 = __builtin_amdgcn_mfma_f32_32x32x16_bf16(afr1[kk], bf, pA1, 0, 0, 0);
            }
            __builtin_amdgcn_s_setprio(0);
            const unsigned kbp = (unsigned)((tt - 1) * 128 + colL) & 0x1FFFu;
            #pragma unroll
            for (int r = 0; r < 16; ++r) {            // epilogue of tile tt-1 (pB): 3 ops/score
                float p0 = __uint_as_float((__float_as_uint(pB0[r]) & 0xFFFFE000u) | kbp);
                b2a[r] = __builtin_amdgcn_fmed3f(p0, b1a[r], b2a[r]);
                b1a[r] = fminf(p0, b1a[r]);
                float p1 = __uint_as_float((__float_as_uint(pB1[r]) & 0xFFFFE000u) | kbp);
                b2b[r] = __builtin_amdgcn_fmed3f(p1, b1b[r], b2b[r]);
                b1b[r] = fminf(p1, b1b[r]);
            }
            #pragma unroll
            for (int r = 0; r < 16; ++r) { pB0[r] = 0.0f; pB1[r] = 0.0f; }
        }
        // ---------- odd tile tt+1: read buf1, stage tt+2 -> buf0; MFMA->pB, epi pA ----------
        __builtin_amdgcn_s_barrier();                 // all waves done reading buf0 (tile tt)
        {
            const char* g_ = gW + (size_t)((tt + 2) & 63) * 65536;
            #pragma unroll
            for (int i = 0; i < 8; ++i)
                ASYNC_COPY16(g_ + i * 1024, smem + wv * 8192 + i * 1024);
        }
        asm volatile("s_waitcnt vmcnt(8)" ::: "memory");
        __builtin_amdgcn_s_barrier();
        __builtin_amdgcn_sched_barrier(0);
        {
            __builtin_amdgcn_s_setprio(1);
            #pragma unroll
            for (int kk = 0; kk < 16; ++kk) {
                bf16x8 bf = *reinterpret_cast<const bf16x8*>(
                    smem + 65536 + cg * 16384 + (kk * 2 + h) * 512 + ln31 * 16);
                pB0 = __builtin_amdgcn_mfma_f32_32x32x16_bf16(afr0[kk], bf, pB0, 0, 0, 0);
                pB1 = __builtin_amdgcn_mfma_f32_32x32x16_bf16(afr1[kk], bf, pB1, 0, 0, 0);
            }
            __builtin_amdgcn_s_setprio(0);
            const unsigned kbp = (unsigned)(tt * 128 + colL);
            #pragma unroll
            for (int r = 0; r < 16; ++r) {            // epilogue of tile tt (pA)
                float p0 = __uint_as_float((__float_as_uint(pA0[r]) & 0xFFFFE000u) | kbp);
                b2a[r] = __builtin_amdgcn_fmed3f(p0, b1a[r], b2a[r]);
                b1a[r] = fminf(p0, b1a[r]);
                float p1 = __uint_as_float((__float_as_uint(pA1[r]) & 0xFFFFE000u) | kbp);
                b2b[r] = __builtin_amdgcn_fmed3f(p1, b1b[r], b2b[r]);
                b1b[r] = fminf(p1, b1b[r]);
            }
            #pragma unroll
            for (int r = 0; r < 16; ++r) { pA0[r] = 0.0f; pA1[r] = 0.0f; }
        }
    }
    {   // final epilogue: tile 63 (in pB)
        const unsigned kbf = (unsigned)(63 * 128 + colL);
        #pragma unroll
        for (int r = 0; r < 16; ++r) {
            float p0 = __uint_as_float((__float_as_uint(pB0[r]) & 0xFFFFE000u) | kbf);
            b2a[r] = __builtin_amdgcn_fmed3f(p0, b1a[r], b2a[r]);
            b1a[r] = fminf(p0, b1a[r]);
            float p1 = __uint_as_float((__float_as_uint(pB1[r]) & 0xFFFFE000u) | kbf);
            b2b[r] = __builtin_amdgcn_fmed3f(p1, b1b[r], b2b[r]);
            b1b[r] = fminf(p1, b1b[r]);
        }
    }

    asm volatile("s_waitcnt vmcnt(0)" ::: "memory");  // drain wrapped stages
    __syncthreads();                                  // safe to alias smem

    // per-row slot arrays in LDS: [128 rows][129 stride], 128 slots per row
    float* sb1 = reinterpret_cast<float*>(smem);      // [128][129]
    float* sb2 = sb1 + 128 * 129;                     // 2x66048 B = 132096 exactly
    #pragma unroll
    for (int r = 0; r < 16; ++r) {
        int rl = rg * 64 + (r & 3) + 8 * (r >> 2) + 4 * h;   // C/D row mapping (verified)
        sb1[rl * 129 + colL] = b1a[r];
        sb2[rl * 129 + colL] = b2a[r];
        sb1[(rl + 32) * 129 + colL] = b1b[r];
        sb2[(rl + 32) * 129 + colL] = b2b[r];
    }
    __syncthreads();
    if (t < 128) {
        float B1 = 3.4e38f, B2 = 3.4e38f;
        for (int c = 0; c < 128; ++c) {
            float a1 = sb1[t * 129 + c], a2 = sb2[t * 129 + c];
            float nb2 = fminf(fmaxf(B1, a1), fminf(B2, a2));  // 2nd-smallest of {B1,B2,a1,a2}
            B1 = fminf(B1, a1);
            B2 = nb2;
        }
        int row = r0 + t;
        idx_out[row] = (float)(__float_as_uint(B1) & 0x1FFFu);
        rowmin[row]  = B1;
        int nc = 0;
        if (B2 - B1 <= M_FLAG) {
            unsigned pos = atomicAdd(flag_count, 1u);
            if (pos < N_ROWS) flags[pos] = row;
            // Lemma: dropped scores in slot L >= final b2(L). If b2(L) > T for all L,
            // {b1(L) <= T} is the complete candidate set; else row is "hard".
            float T = B1 + M_CAND;
            bool hard = false;
            for (int c = 0; c < 128; ++c) {
                float a1 = sb1[t * 129 + c];
                if (a1 <= T) {
                    if (nc < CAP) cands[row * CAP + nc] = (int)(__float_as_uint(a1) & 0x1FFFu);
                    ++nc;
                }
                if (sb2[t * 129 + c] <= T) hard = true;
            }
            if (nc > CAP) hard = true;
            if (hard) {
                nc = 0;
                unsigned hp = atomicAdd(hard_count, 1u);
                if (hp < N_ROWS) hard_flags[hp] = row;
            }
        }
        candcnt[row] = nc;
    }
}

// Full re-sweep for rare "hard" rows (4 waves, 64-col blocks; raw acc vs wsq-free thr).
__global__ __launch_bounds__(256, 2) void fixup_kernel(
        const float* __restrict__ x, const ushort* __restrict__ wbf,
        const float* __restrict__ rowmin,
        const int* __restrict__ hard_flags, const unsigned* __restrict__ hard_count,
        int* __restrict__ candcnt, int* __restrict__ cands) {
    __shared__ __align__(16) ushort wt[64 * 256];     // 32KB: two 16KB 32-col groups
    __shared__ int   sh_rows[64];
    __shared__ float sh_thr[64];

    const int t = threadIdx.x;
    const int lane = t & 63, ln31 = lane & 31, h = lane >> 5;
    const int wv = t >> 6, rs = wv & 1, cs = wv >> 1;  // 4 waves: 2 rs x 2 cs
    const int colL = cs * 32 + ln31;

    unsigned cu = hard_count[0];
    int cnt = cu > N_ROWS ? N_ROWS : (int)cu;
    int nunits = ((cnt + 63) >> 6) * 8;

    for (int u = blockIdx.x; u < nunits; u += 512) {
        int ksp  = u & 7;
        int base = (u >> 3) * 64;
        int nrows = cnt - base; if (nrows > 64) nrows = 64;

        __syncthreads();
        if (t < 64) {
            int valid = (t < nrows);
            int gr = hard_flags[base + (valid ? t : 0)];
            sh_rows[t] = gr;
            sh_thr[t]  = valid ? rowmin[gr] + M_CAND : -3.4e38f;
        }
        __syncthreads();

        int arow = sh_rows[rs * 32 + ln31];
        const float4* xr = reinterpret_cast<const float4*>(x) + (size_t)arow * 64;
        bf16x8 afr[16];
        #pragma unroll
        for (int kk = 0; kk < 16; ++kk)
            afr[kk] = __builtin_bit_cast(bf16x8, pack8(xr[kk * 4 + h * 2], xr[kk * 4 + h * 2 + 1]));
        float thr_r[16];
        int   rl_r[16];
        #pragma unroll
        for (int r = 0; r < 16; ++r) {
            rl_r[r]  = rs * 32 + (r & 3) + 8 * (r >> 2) + 4 * h;
            thr_r[r] = sh_thr[rl_r[r]];
        }

        for (int tb = 0; tb < 16; ++tb) {
            int blk = ksp * 16 + tb;                  // 64-col block
            __syncthreads();
            {
                const char* g = (const char*)wbf + (size_t)blk * 32768
                              + (size_t)wv * 8192 + (size_t)lane * 16;
                char* l = (char*)wt + wv * 8192;
                #pragma unroll
                for (int i = 0; i < 8; ++i) ASYNC_COPY16(g + i * 1024, l + i * 1024);
            }
            __syncthreads();

            int kcol = blk * 64 + colL;
            f32x16 acc = {0,0,0,0,0,0,0,0,0,0,0,0,0,0,0,0};
            #pragma unroll
            for (int kk = 0; kk < 16; ++kk) {
                bf16x8 bf = *reinterpret_cast<const bf16x8*>(
                    &wt[cs * 8192 + (kk * 2 + h) * 256 + ln31 * 8]);
                acc = __builtin_amdgcn_mfma_f32_32x32x16_bf16(afr[kk], bf, acc, 0, 0, 0);
            }
            #pragma unroll
            for (int r = 0; r < 16; ++r) {
                float s0 = acc[r];                     // wsq-free, consistent with rowmin
                if (s0 <= thr_r[r]) {
                    int grow = sh_rows[rl_r[r]];
                    int pos = atomicAdd(&candcnt[grow], 1);
                    if (pos < CAP) cands[grow * CAP + pos] = kcol;
                }
            }
        }
    }
}

// np-exact rescore (verified R3): q = fl32(fl32(Xsq - 2*fl32(dot64)) + Wsq), lowest-index ties.
__global__ __launch_bounds__(256) void rescore_kernel(
        const float* __restrict__ x, const float* __restrict__ w,
        const float* __restrict__ wsq,
        const int* __restrict__ flags, const unsigned* __restrict__ flag_count,
        const int* __restrict__ candcnt, const int* __restrict__ cands,
        float* __restrict__ idx_out) {
    int wid  = (blockIdx.x * 256 + threadIdx.x) >> 6;
    int lane = threadIdx.x & 63;
    unsigned cu = flag_count[0];
    int cnt = (cu > N_ROWS) ? N_ROWS : (int)cu;

    for (int fi = wid; fi < cnt; fi += 1024) {
        int row = flags[fi];
        float4 xv = reinterpret_cast<const float4*>(x)[(size_t)row * 64 + lane];
        double xs = (double)xv.x * xv.x + (double)xv.y * xv.y
                  + (double)xv.z * xv.z + (double)xv.w * xv.w;
        #pragma unroll
        for (int off = 1; off < 64; off <<= 1) xs += __shfl_xor(xs, off, 64);
        float Xs = (float)xs;
        int nc = candcnt[row]; if (nc > CAP) nc = CAP;
        float bq = 3.4e38f; int bk = -1;
        for (int c = 0; c < nc; ++c) {
            int k = cands[row * CAP + c];
            float4 wv = reinterpret_cast<const float4*>(w)[(size_t)k * 64 + lane];
            double d = (double)xv.x * wv.x + (double)xv.y * wv.y
                     + (double)xv.z * wv.z + (double)xv.w * wv.w;
            #pragma unroll
            for (int off = 1; off < 64; off <<= 1) d += __shfl_xor(d, off, 64);
            float XW = (float)d;
            float t3 = fmaf(-2.0f, XW, Xs);
            float qv = t3 + wsq[k];
            if (qv < bq || (qv == bq && k < bk) || bk < 0) { bq = qv; bk = k; }
        }
        if (lane == 0 && bk >= 0) idx_out[row] = (float)bk;
    }
}

__global__ __launch_bounds__(256) void gather_loss_kernel(
        const float* __restrict__ x, const float* __restrict__ w,
        const float* __restrict__ idx_f, float* __restrict__ out_q,
        float* __restrict__ accum) {
    const int nf4 = Q_ELEMS / 4;
    float lsum = 0.0f;
    for (int e = blockIdx.x * blockDim.x + threadIdx.x; e < nf4;
         e += gridDim.x * blockDim.x) {
        int row = e >> 6, d4 = e & 63;
        int k = (int)idx_f[row];
        float4 xv = reinterpret_cast<const float4*>(x)[e];
        float4 qv = reinterpret_cast<const float4*>(w)[(size_t)k * 64 + d4];
        float4 ov;
        ov.x = xv.x + (qv.x - xv.x);
        ov.y = xv.y + (qv.y - xv.y);
        ov.z = xv.z + (qv.z - xv.z);
        ov.w = xv.w + (qv.w - xv.w);
        reinterpret_cast<float4*>(out_q)[e] = ov;
        float dx = xv.x - qv.x, dy = xv.y - qv.y, dz = xv.z - qv.z, dw = xv.w - qv.w;
        lsum += dx * dx + dy * dy + dz * dz + dw * dw;
    }
    #pragma unroll
    for (int off = 32; off > 0; off >>= 1) lsum += __shfl_down(lsum, off, 64);
    __shared__ float ssum[4];
    if ((threadIdx.x & 63) == 0) ssum[threadIdx.x >> 6] = lsum;
    __syncthreads();
    if (threadIdx.x == 0)
        atomicAdd(accum, ssum[0] + ssum[1] + ssum[2] + ssum[3]);
}

__global__ void finalize_kernel(const float* __restrict__ accum,
                                float* __restrict__ out_tail) {
    float mse = accum[0] / (float)Q_ELEMS;
    float commit = 0.25f * mse;
    out_tail[0] = commit;
    out_tail[1] = mse;
    out_tail[2] = commit + mse;
}

extern "C" void kernel_launch(void* const* d_in, const int* in_sizes, int n_in,
                              void* d_out, int out_size, void* d_ws, size_t ws_size,
                              hipStream_t stream) {
    const float* x = (const float*)d_in[0];
    const float* w = (const float*)d_in[1];
    float* out = (float*)d_out;

    char* ws = (char*)d_ws;
    float*    Wsq        = (float*)ws;
    float*    Rmin       = (float*)(ws + 163840);
    float*    accum      = (float*)(ws + 294912);
    unsigned* flag_count = (unsigned*)(ws + 294916);
    unsigned* hard_count = (unsigned*)(ws + 294920);
    int*      flags      = (int*)(ws + 294924);
    int*      hard_flags = (int*)(ws + 425996);
    int*      candcnt    = (int*)(ws + 557068);
    int*      cands      = (int*)(ws + 688140);
    ushort*   Wbf        = (ushort*)(ws + 2785296);

    hipMemsetAsync(ws + 294912, 0, 12, stream);   // accum + flag_count + hard_count
    wsq_wbf_kernel<<<K_CB / 64, 256, 0, stream>>>(w, Wsq, Wbf);
    pass1_kernel<<<N_ROWS / 128, 512, 0, stream>>>(x, Wbf, out + Q_ELEMS,
                                                   Rmin, flags, flag_count,
                                                   hard_flags, hard_count,
                                                   candcnt, cands);
    fixup_kernel<<<512, 256, 0, stream>>>(x, Wbf, Rmin, hard_flags, hard_count,
                                          candcnt, cands);
    rescore_kernel<<<256, 256, 0, stream>>>(x, w, Wsq, flags, flag_count,
                                            candcnt, cands, out + Q_ELEMS);
    gather_loss_kernel<<<8192, 256, 0, stream>>>(x, w, out + Q_ELEMS, out, accum);
    finalize_kernel<<<1, 1, 0, stream>>>(accum, out + Q_ELEMS + N_ROWS);
}

// Round 7
// 474.491 us; speedup vs baseline: 1.2415x; 1.2415x over previous
//
#include <hip/hip_runtime.h>

#define K_CB   8192
#define D_DIM  256
#define N_ROWS 32768
#define Q_ELEMS (N_ROWS * D_DIM)

#define M_FLAG 1.3e-4f   // np-window 6.1e-5 + bf16 score noise + 13-bit pack + wsq-omission (<4e-6)
#define M_CAND 1.3e-4f
#define CAP    16

typedef __bf16 bf16x8 __attribute__((ext_vector_type(8)));
typedef float  f32x16 __attribute__((ext_vector_type(16)));

// async 16B global->LDS DMA: LDS dest is WAVE-UNIFORM base; HW adds lane*16.
#define ASYNC_COPY16(gp, lp)                                              \
    __builtin_amdgcn_global_load_lds(                                     \
        (const __attribute__((address_space(1))) unsigned int*)(gp),      \
        (__attribute__((address_space(3))) unsigned int*)(lp), 16, 0, 0)

// ws layout (bytes):
//   0        Wsq        [8192 f32]   (rescore only)
//   32768    Xsq        [32768 f32]  (slot kept)
//   163840   Rmin       [32768 f32]  (packed b1, NO wsq: low 13 mantissa bits = k)
//   294912   accum f32 | 294916 flag_count u32 | 294920 hard_count u32  (memset 12B)
//   294924   flags      [32768 i32]
//   425996   hard_flags [32768 i32]
//   557068   candcnt    [32768 i32]
//   688140   cands      [32768*16 i32]
//   2785296  Wbf        [8192*256 ushort] = bf16(-2w), 32-COL-GROUP slice-major:
//            byte(k,s) = (k>>5)*16384 + s*512 + (k&31)*16   (s = d/8, 8 bf16 per 16B)
//            -> 128-col tile T = bytes [T*65536,+65536) contiguous; identity DMA;
//               ds_read_b128 = 32 consecutive 16B per half-wave, conflict-free.

__device__ inline ushort f2bf(float f) {          // RNE float->bf16
    unsigned u = __float_as_uint(f);
    unsigned r = u + 0x7FFFu + ((u >> 16) & 1u);
    return (ushort)(r >> 16);
}

__device__ inline uint4 pack8(float4 a, float4 b) {
    uint4 o;
    o.x = (unsigned)f2bf(a.x) | ((unsigned)f2bf(a.y) << 16);
    o.y = (unsigned)f2bf(a.z) | ((unsigned)f2bf(a.w) << 16);
    o.z = (unsigned)f2bf(b.x) | ((unsigned)f2bf(b.y) << 16);
    o.w = (unsigned)f2bf(b.z) | ((unsigned)f2bf(b.w) << 16);
    return o;
}

// fused: np-exact w_sq (fp64 sum -> fp32, EXACT old shuffle-tree order) +
// Wbf = bf16(-2w) in 32-col-group slice-major layout.
__global__ __launch_bounds__(256) void wsq_wbf_kernel(const float* __restrict__ w,
                                                      float* __restrict__ wsq,
                                                      ushort* __restrict__ wbf) {
    __shared__ __align__(16) ushort tile[64 * 256];   // 32KB: two 16KB 32-col groups
    const int t = threadIdx.x;
    const int kb = blockIdx.x;                        // 128 blocks of 64 codewords
    const int wv = t >> 6, lane = t & 63;

    const float4* wb = reinterpret_cast<const float4*>(w) + (size_t)kb * 4096;
    #pragma unroll
    for (int i = 0; i < 16; ++i) {
        int j = i * 256 + t;                          // float4 idx: c = j>>6, d4 = j&63
        float4 v = wb[j];
        int c = j >> 6, d4 = j & 63;
        uint2 o;
        o.x = (unsigned)f2bf(-2.0f * v.x) | ((unsigned)f2bf(-2.0f * v.y) << 16);
        o.y = (unsigned)f2bf(-2.0f * v.z) | ((unsigned)f2bf(-2.0f * v.w) << 16);
        *reinterpret_cast<uint2*>((char*)tile + (size_t)(c >> 5) * 16384
                                  + (size_t)(d4 >> 1) * 512 + (c & 31) * 16 + (d4 & 1) * 8) = o;
    }

    for (int c = wv; c < 64; c += 4) {
        float4 v = reinterpret_cast<const float4*>(w)[(size_t)(kb * 64 + c) * 64 + lane];
        double sq = (double)v.x * v.x + (double)v.y * v.y + (double)v.z * v.z + (double)v.w * v.w;
        #pragma unroll
        for (int off = 32; off > 0; off >>= 1) sq += __shfl_down(sq, off, 64);
        if (lane == 0) wsq[kb * 64 + c] = (float)sq;
    }

    __syncthreads();
    const uint4* src = reinterpret_cast<const uint4*>(tile);
    uint4* dst = reinterpret_cast<uint4*>((char*)wbf + (size_t)kb * 32768);
    #pragma unroll
    for (int j = 0; j < 8; ++j) dst[j * 256 + t] = src[j * 256 + t];
}

// Pass 1 (R7): R3 verified skeleton + 4 INDEPENDENT MFMA CHAINS per wave
// (2 row-streams x 2 k-halves, interleaved issue) to probe dependent-MFMA
// latency as the binder (C: 4 -> 8 chains/SIMD). wsq-free scoring (R6-verified).
// 128 rows/block, 8 waves = 2 rg x 4 cg, 128-col tiles, 64 iters, dbuf 2x64KB.
__global__ __launch_bounds__(512, 2) void pass1_kernel(
        const float* __restrict__ x, const ushort* __restrict__ wbf,
        float* __restrict__ idx_out,
        float* __restrict__ rowmin, int* __restrict__ flags,
        unsigned* __restrict__ flag_count, int* __restrict__ hard_flags,
        unsigned* __restrict__ hard_count, int* __restrict__ candcnt,
        int* __restrict__ cands) {
    __shared__ __align__(16) char smem[132096];       // 2x64KB staging / 2x[128][129] f32

    const int t = threadIdx.x;
    const int lane = t & 63, ln31 = lane & 31, h = lane >> 5;
    const int wv = t >> 6;                            // 0..7
    const int rg = wv >> 2;                           // 0..1 (64-row group)
    const int cg = wv & 3;                            // 0..3 (32-col group)
    const int colL = cg * 32 + ln31;                  // 0..127 in tile
    const int r0 = blockIdx.x * 128;

    const char* gW = (const char*)wbf + (size_t)wv * 8192 + (size_t)lane * 16;

    // A fragments: TWO 32-row streams (verified mapping)
    const int arow0 = r0 + rg * 64 + ln31;
    const float4* xr0 = reinterpret_cast<const float4*>(x) + (size_t)arow0 * 64;
    const float4* xr1 = xr0 + (size_t)32 * 64;
    bf16x8 afr0[16], afr1[16];
    #pragma unroll
    for (int kk = 0; kk < 16; ++kk) {
        afr0[kk] = __builtin_bit_cast(bf16x8, pack8(xr0[kk * 4 + h * 2], xr0[kk * 4 + h * 2 + 1]));
        afr1[kk] = __builtin_bit_cast(bf16x8, pack8(xr1[kk * 4 + h * 2], xr1[kk * 4 + h * 2 + 1]));
    }

    // prologue: stage tile 0 into buf0 (8 x 1KB per wave)
    #pragma unroll
    for (int i = 0; i < 8; ++i) ASYNC_COPY16(gW + i * 1024, smem + wv * 8192 + i * 1024);

    float b1a[16], b2a[16], b1b[16], b2b[16];
    #pragma unroll
    for (int r = 0; r < 16; ++r) { b1a[r] = 3.4e38f; b2a[r] = 3.4e38f;
                                   b1b[r] = 3.4e38f; b2b[r] = 3.4e38f; }

    for (int it = 0; it < 64; ++it) {
        __builtin_amdgcn_s_barrier();                 // all waves done reading buf[(it+1)&1]
        {   // prefetch tile it+1 into the freed buffer
            const int nt = (it + 1) & 63;
            const char* g = gW + (size_t)nt * 65536;
            char* l = smem + ((it + 1) & 1) * 65536 + wv * 8192;
            #pragma unroll
            for (int i = 0; i < 8; ++i) ASYNC_COPY16(g + i * 1024, l + i * 1024);
        }
        // counted wait: tile it+1's 8 copies stay in flight; tile it fully landed
        asm volatile("s_waitcnt vmcnt(8)" ::: "memory");
        __builtin_amdgcn_s_barrier();                 // every wave waited -> tile resident
        __builtin_amdgcn_sched_barrier(0);

        const char* bt = smem + (it & 1) * 65536 + cg * 16384 + ln31 * 16;

        // FOUR independent accumulator chains: {stream0,stream1} x {k-lo, k-hi}
        f32x16 a0l = {0,0,0,0,0,0,0,0,0,0,0,0,0,0,0,0};
        f32x16 a1l = {0,0,0,0,0,0,0,0,0,0,0,0,0,0,0,0};
        f32x16 a0h = {0,0,0,0,0,0,0,0,0,0,0,0,0,0,0,0};
        f32x16 a1h = {0,0,0,0,0,0,0,0,0,0,0,0,0,0,0,0};
        __builtin_amdgcn_s_setprio(1);
        #pragma unroll
        for (int kk = 0; kk < 8; ++kk) {              // 2 B-reads feed 4 indep MFMAs
            bf16x8 bfl = *reinterpret_cast<const bf16x8*>(bt + (kk * 2 + h) * 512);
            bf16x8 bfh = *reinterpret_cast<const bf16x8*>(bt + ((kk + 8) * 2 + h) * 512);
            a0l = __builtin_amdgcn_mfma_f32_32x32x16_bf16(afr0[kk],     bfl, a0l, 0, 0, 0);
            a1l = __builtin_amdgcn_mfma_f32_32x32x16_bf16(afr1[kk],     bfl, a1l, 0, 0, 0);
            a0h = __builtin_amdgcn_mfma_f32_32x32x16_bf16(afr0[kk + 8], bfh, a0h, 0, 0, 0);
            a1h = __builtin_amdgcn_mfma_f32_32x32x16_bf16(afr1[kk + 8], bfh, a1h, 0, 0, 0);
        }
        __builtin_amdgcn_s_setprio(0);

        const int kb = it * 128 + colL;
        #pragma unroll
        for (int r = 0; r < 16; ++r) {                // merge halves + 3-op min-track
            float s0 = a0l[r] + a0h[r];
            float p0 = __uint_as_float((__float_as_uint(s0) & 0xFFFFE000u) | (unsigned)kb);
            b2a[r] = __builtin_amdgcn_fmed3f(p0, b1a[r], b2a[r]);
            b1a[r] = fminf(p0, b1a[r]);
            float s1 = a1l[r] + a1h[r];
            float p1 = __uint_as_float((__float_as_uint(s1) & 0xFFFFE000u) | (unsigned)kb);
            b2b[r] = __builtin_amdgcn_fmed3f(p1, b1b[r], b2b[r]);
            b1b[r] = fminf(p1, b1b[r]);
        }
    }

    __syncthreads();   // full drain (incl. wrapped redundant stage) before aliasing smem

    // per-row slot arrays in LDS: [128 rows][129 stride], 128 slots per row
    float* sb1 = reinterpret_cast<float*>(smem);      // [128][129]
    float* sb2 = sb1 + 128 * 129;                     // 2x66048 B = 132096 exactly
    #pragma unroll
    for (int r = 0; r < 16; ++r) {
        int rl = rg * 64 + (r & 3) + 8 * (r >> 2) + 4 * h;   // C/D row mapping (verified)
        sb1[rl * 129 + colL] = b1a[r];
        sb2[rl * 129 + colL] = b2a[r];
        sb1[(rl + 32) * 129 + colL] = b1b[r];
        sb2[(rl + 32) * 129 + colL] = b2b[r];
    }
    __syncthreads();
    if (t < 128) {
        float B1 = 3.4e38f, B2 = 3.4e38f;
        for (int c = 0; c < 128; ++c) {
            float a1 = sb1[t * 129 + c], a2 = sb2[t * 129 + c];
            float nb2 = fminf(fmaxf(B1, a1), fminf(B2, a2));  // 2nd-smallest of {B1,B2,a1,a2}
            B1 = fminf(B1, a1);
            B2 = nb2;
        }
        int row = r0 + t;
        idx_out[row] = (float)(__float_as_uint(B1) & 0x1FFFu);
        rowmin[row]  = B1;
        int nc = 0;
        if (B2 - B1 <= M_FLAG) {
            unsigned pos = atomicAdd(flag_count, 1u);
            if (pos < N_ROWS) flags[pos] = row;
            // Lemma: dropped scores in slot L >= final b2(L). If b2(L) > T for all L,
            // {b1(L) <= T} is the complete candidate set; else row is "hard".
            float T = B1 + M_CAND;
            bool hard = false;
            for (int c = 0; c < 128; ++c) {
                float a1 = sb1[t * 129 + c];
                if (a1 <= T) {
                    if (nc < CAP) cands[row * CAP + nc] = (int)(__float_as_uint(a1) & 0x1FFFu);
                    ++nc;
                }
                if (sb2[t * 129 + c] <= T) hard = true;
            }
            if (nc > CAP) hard = true;
            if (hard) {
                nc = 0;
                unsigned hp = atomicAdd(hard_count, 1u);
                if (hp < N_ROWS) hard_flags[hp] = row;
            }
        }
        candcnt[row] = nc;
    }
}

// Full re-sweep for rare "hard" rows (4 waves, 64-col blocks; raw acc vs wsq-free thr).
__global__ __launch_bounds__(256, 2) void fixup_kernel(
        const float* __restrict__ x, const ushort* __restrict__ wbf,
        const float* __restrict__ rowmin,
        const int* __restrict__ hard_flags, const unsigned* __restrict__ hard_count,
        int* __restrict__ candcnt, int* __restrict__ cands) {
    __shared__ __align__(16) ushort wt[64 * 256];     // 32KB: two 16KB 32-col groups
    __shared__ int   sh_rows[64];
    __shared__ float sh_thr[64];

    const int t = threadIdx.x;
    const int lane = t & 63, ln31 = lane & 31, h = lane >> 5;
    const int wv = t >> 6, rs = wv & 1, cs = wv >> 1;  // 4 waves: 2 rs x 2 cs
    const int colL = cs * 32 + ln31;

    unsigned cu = hard_count[0];
    int cnt = cu > N_ROWS ? N_ROWS : (int)cu;
    int nunits = ((cnt + 63) >> 6) * 8;

    for (int u = blockIdx.x; u < nunits; u += 512) {
        int ksp  = u & 7;
        int base = (u >> 3) * 64;
        int nrows = cnt - base; if (nrows > 64) nrows = 64;

        __syncthreads();
        if (t < 64) {
            int valid = (t < nrows);
            int gr = hard_flags[base + (valid ? t : 0)];
            sh_rows[t] = gr;
            sh_thr[t]  = valid ? rowmin[gr] + M_CAND : -3.4e38f;
        }
        __syncthreads();

        int arow = sh_rows[rs * 32 + ln31];
        const float4* xr = reinterpret_cast<const float4*>(x) + (size_t)arow * 64;
        bf16x8 afr[16];
        #pragma unroll
        for (int kk = 0; kk < 16; ++kk)
            afr[kk] = __builtin_bit_cast(bf16x8, pack8(xr[kk * 4 + h * 2], xr[kk * 4 + h * 2 + 1]));
        float thr_r[16];
        int   rl_r[16];
        #pragma unroll
        for (int r = 0; r < 16; ++r) {
            rl_r[r]  = rs * 32 + (r & 3) + 8 * (r >> 2) + 4 * h;
            thr_r[r] = sh_thr[rl_r[r]];
        }

        for (int tb = 0; tb < 16; ++tb) {
            int blk = ksp * 16 + tb;                  // 64-col block
            __syncthreads();
            {
                const char* g = (const char*)wbf + (size_t)blk * 32768
                              + (size_t)wv * 8192 + (size_t)lane * 16;
                char* l = (char*)wt + wv * 8192;
                #pragma unroll
                for (int i = 0; i < 8; ++i) ASYNC_COPY16(g + i * 1024, l + i * 1024);
            }
            __syncthreads();

            int kcol = blk * 64 + colL;
            f32x16 acc = {0,0,0,0,0,0,0,0,0,0,0,0,0,0,0,0};
            #pragma unroll
            for (int kk = 0; kk < 16; ++kk) {
                bf16x8 bf = *reinterpret_cast<const bf16x8*>(
                    &wt[cs * 8192 + (kk * 2 + h) * 256 + ln31 * 8]);
                acc = __builtin_amdgcn_mfma_f32_32x32x16_bf16(afr[kk], bf, acc, 0, 0, 0);
            }
            #pragma unroll
            for (int r = 0; r < 16; ++r) {
                float s0 = acc[r];                     // wsq-free, consistent with rowmin
                if (s0 <= thr_r[r]) {
                    int grow = sh_rows[rl_r[r]];
                    int pos = atomicAdd(&candcnt[grow], 1);
                    if (pos < CAP) cands[grow * CAP + pos] = kcol;
                }
            }
        }
    }
}

// np-exact rescore (verified R3): q = fl32(fl32(Xsq - 2*fl32(dot64)) + Wsq), lowest-index ties.
__global__ __launch_bounds__(256) void rescore_kernel(
        const float* __restrict__ x, const float* __restrict__ w,
        const float* __restrict__ wsq,
        const int* __restrict__ flags, const unsigned* __restrict__ flag_count,
        const int* __restrict__ candcnt, const int* __restrict__ cands,
        float* __restrict__ idx_out) {
    int wid  = (blockIdx.x * 256 + threadIdx.x) >> 6;
    int lane = threadIdx.x & 63;
    unsigned cu = flag_count[0];
    int cnt = (cu > N_ROWS) ? N_ROWS : (int)cu;

    for (int fi = wid; fi < cnt; fi += 1024) {
        int row = flags[fi];
        float4 xv = reinterpret_cast<const float4*>(x)[(size_t)row * 64 + lane];
        double xs = (double)xv.x * xv.x + (double)xv.y * xv.y
                  + (double)xv.z * xv.z + (double)xv.w * xv.w;
        #pragma unroll
        for (int off = 1; off < 64; off <<= 1) xs += __shfl_xor(xs, off, 64);
        float Xs = (float)xs;
        int nc = candcnt[row]; if (nc > CAP) nc = CAP;
        float bq = 3.4e38f; int bk = -1;
        for (int c = 0; c < nc; ++c) {
            int k = cands[row * CAP + c];
            float4 wv = reinterpret_cast<const float4*>(w)[(size_t)k * 64 + lane];
            double d = (double)xv.x * wv.x + (double)xv.y * wv.y
                     + (double)xv.z * wv.z + (double)xv.w * wv.w;
            #pragma unroll
            for (int off = 1; off < 64; off <<= 1) d += __shfl_xor(d, off, 64);
            float XW = (float)d;
            float t3 = fmaf(-2.0f, XW, Xs);
            float qv = t3 + wsq[k];
            if (qv < bq || (qv == bq && k < bk) || bk < 0) { bq = qv; bk = k; }
        }
        if (lane == 0 && bk >= 0) idx_out[row] = (float)bk;
    }
}

__global__ __launch_bounds__(256) void gather_loss_kernel(
        const float* __restrict__ x, const float* __restrict__ w,
        const float* __restrict__ idx_f, float* __restrict__ out_q,
        float* __restrict__ accum) {
    const int nf4 = Q_ELEMS / 4;
    float lsum = 0.0f;
    for (int e = blockIdx.x * blockDim.x + threadIdx.x; e < nf4;
         e += gridDim.x * blockDim.x) {
        int row = e >> 6, d4 = e & 63;
        int k = (int)idx_f[row];
        float4 xv = reinterpret_cast<const float4*>(x)[e];
        float4 qv = reinterpret_cast<const float4*>(w)[(size_t)k * 64 + d4];
        float4 ov;
        ov.x = xv.x + (qv.x - xv.x);
        ov.y = xv.y + (qv.y - xv.y);
        ov.z = xv.z + (qv.z - xv.z);
        ov.w = xv.w + (qv.w - xv.w);
        reinterpret_cast<float4*>(out_q)[e] = ov;
        float dx = xv.x - qv.x, dy = xv.y - qv.y, dz = xv.z - qv.z, dw = xv.w - qv.w;
        lsum += dx * dx + dy * dy + dz * dz + dw * dw;
    }
    #pragma unroll
    for (int off = 32; off > 0; off >>= 1) lsum += __shfl_down(lsum, off, 64);
    __shared__ float ssum[4];
    if ((threadIdx.x & 63) == 0) ssum[threadIdx.x >> 6] = lsum;
    __syncthreads();
    if (threadIdx.x == 0)
        atomicAdd(accum, ssum[0] + ssum[1] + ssum[2] + ssum[3]);
}

__global__ void finalize_kernel(const float* __restrict__ accum,
                                float* __restrict__ out_tail) {
    float mse = accum[0] / (float)Q_ELEMS;
    float commit = 0.25f * mse;
    out_tail[0] = commit;
    out_tail[1] = mse;
    out_tail[2] = commit + mse;
}

extern "C" void kernel_launch(void* const* d_in, const int* in_sizes, int n_in,
                              void* d_out, int out_size, void* d_ws, size_t ws_size,
                              hipStream_t stream) {
    const float* x = (const float*)d_in[0];
    const float* w = (const float*)d_in[1];
    float* out = (float*)d_out;

    char* ws = (char*)d_ws;
    float*    Wsq        = (float*)ws;
    float*    Rmin       = (float*)(ws + 163840);
    float*    accum      = (float*)(ws + 294912);
    unsigned* flag_count = (unsigned*)(ws + 294916);
    unsigned* hard_count = (unsigned*)(ws + 294920);
    int*      flags      = (int*)(ws + 294924);
    int*      hard_flags = (int*)(ws + 425996);
    int*      candcnt    = (int*)(ws + 557068);
    int*      cands      = (int*)(ws + 688140);
    ushort*   Wbf        = (ushort*)(ws + 2785296);

    hipMemsetAsync(ws + 294912, 0, 12, stream);   // accum + flag_count + hard_count
    wsq_wbf_kernel<<<K_CB / 64, 256, 0, stream>>>(w, Wsq, Wbf);
    pass1_kernel<<<N_ROWS / 128, 512, 0, stream>>>(x, Wbf, out + Q_ELEMS,
                                                   Rmin, flags, flag_count,
                                                   hard_flags, hard_count,
                                                   candcnt, cands);
    fixup_kernel<<<512, 256, 0, stream>>>(x, Wbf, Rmin, hard_flags, hard_count,
                                          candcnt, cands);
    rescore_kernel<<<256, 256, 0, stream>>>(x, w, Wsq, flags, flag_count,
                                            candcnt, cands, out + Q_ELEMS);
    gather_loss_kernel<<<8192, 256, 0, stream>>>(x, w, out + Q_ELEMS, out, accum);
    finalize_kernel<<<1, 1, 0, stream>>>(accum, out + Q_ELEMS + N_ROWS);
}

// Round 10
// 400.789 us; speedup vs baseline: 1.4698x; 1.1839x over previous
//
#include <hip/hip_runtime.h>

#define K_CB   8192
#define D_DIM  256
#define N_ROWS 32768
#define Q_ELEMS (N_ROWS * D_DIM)

#define M_FLAG 1.3e-4f   // np-window 6.1e-5 + bf16 score noise + 13-bit pack + wsq-omission (<4e-6)
#define M_CAND 1.3e-4f
#define CAP    16

typedef __bf16 bf16x8 __attribute__((ext_vector_type(8)));
typedef float  f32x16 __attribute__((ext_vector_type(16)));

// async 16B global->LDS DMA: LDS dest is WAVE-UNIFORM base; HW adds lane*16.
#define ASYNC_COPY16(gp, lp)                                              \
    __builtin_amdgcn_global_load_lds(                                     \
        (const __attribute__((address_space(1))) unsigned int*)(gp),      \
        (__attribute__((address_space(3))) unsigned int*)(lp), 16, 0, 0)

// ws layout (bytes):
//   0        Wsq        [8192 f32]   (rescore only)
//   32768    Xsq        [32768 f32]  (slot kept)
//   163840   Rmin       [32768 f32]  (packed b1, NO wsq: low 13 mantissa bits = k)
//   294912   accum f32 | 294916 flag_count u32 | 294920 hard_count u32  (memset 12B)
//   294924   flags      [32768 i32]
//   425996   hard_flags [32768 i32]
//   557068   candcnt    [32768 i32]
//   688140   cands      [32768*16 i32]
//   2785296  Wbf        [8192*256 ushort] = bf16(-2w), K-SLICE-MAJOR layout (R1-verified):
//            byte(k,s) = (k>>6)*32768 + s*1024 + (k&63)*16   (s = d/8, 8 bf16 per 16B)
//            -> LDS staging is an identity copy; fragment ds_read_b128 is 32
//               consecutive 16B per half-wave = conflict-free, no swizzle.

__device__ inline ushort f2bf(float f) {          // RNE float->bf16
    unsigned u = __float_as_uint(f);
    unsigned r = u + 0x7FFFu + ((u >> 16) & 1u);
    return (ushort)(r >> 16);
}

__device__ inline uint4 pack8(float4 a, float4 b) {
    uint4 o;
    o.x = (unsigned)f2bf(a.x) | ((unsigned)f2bf(a.y) << 16);
    o.y = (unsigned)f2bf(a.z) | ((unsigned)f2bf(a.w) << 16);
    o.z = (unsigned)f2bf(b.x) | ((unsigned)f2bf(b.y) << 16);
    o.w = (unsigned)f2bf(b.z) | ((unsigned)f2bf(b.w) << 16);
    return o;
}

// fused: np-exact w_sq (fp64 sum -> fp32, EXACT old shuffle-tree order) +
// Wbf = bf16(-2w) in K-slice-major layout. (R1-verbatim: ran at 408.5 us, absmax 0.)
__global__ __launch_bounds__(256) void wsq_wbf_kernel(const float* __restrict__ w,
                                                      float* __restrict__ wsq,
                                                      ushort* __restrict__ wbf) {
    __shared__ __align__(16) ushort tile[64 * 256];   // 32KB slice-major [s32][c64][8]
    const int t = threadIdx.x;
    const int kb = blockIdx.x;                        // 128 blocks of 64 codewords
    const int wv = t >> 6, lane = t & 63;

    // phase 1: coalesced read + bf16(-2w) scatter into LDS slice-major
    const float4* wb = reinterpret_cast<const float4*>(w) + (size_t)kb * 4096;
    #pragma unroll
    for (int i = 0; i < 16; ++i) {
        int j = i * 256 + t;                          // float4 idx: c = j>>6, d4 = j&63
        float4 v = wb[j];
        int c = j >> 6, d4 = j & 63;
        uint2 o;
        o.x = (unsigned)f2bf(-2.0f * v.x) | ((unsigned)f2bf(-2.0f * v.y) << 16);
        o.y = (unsigned)f2bf(-2.0f * v.z) | ((unsigned)f2bf(-2.0f * v.w) << 16);
        *reinterpret_cast<uint2*>((char*)tile + (size_t)(d4 >> 1) * 1024 + c * 16 + (d4 & 1) * 8) = o;
    }

    // phase 2: wsq with the exact old math (per-lane 4-term double + shfl_down tree)
    for (int c = wv; c < 64; c += 4) {
        float4 v = reinterpret_cast<const float4*>(w)[(size_t)(kb * 64 + c) * 64 + lane];
        double sq = (double)v.x * v.x + (double)v.y * v.y + (double)v.z * v.z + (double)v.w * v.w;
        #pragma unroll
        for (int off = 32; off > 0; off >>= 1) sq += __shfl_down(sq, off, 64);
        if (lane == 0) wsq[kb * 64 + c] = (float)sq;
    }

    __syncthreads();
    // phase 3: coalesced 32KB writeout
    const uint4* src = reinterpret_cast<const uint4*>(tile);
    uint4* dst = reinterpret_cast<uint4*>((char*)wbf + (size_t)kb * 32768);
    #pragma unroll
    for (int j = 0; j < 8; ++j) dst[j * 256 + t] = src[j * 256 + t];
}

// Pass 1: EXACT Round-1 skeleton (fastest measured pass1: 183 us, absmax 0, VGPR 64) —
// 128 rows/block (512 thr, 8 waves = 4 rs x 2 cs), 64-col tiles, double-buffered
// LDS, prefetch-before-compute, ONE __syncthreads per iteration. Sole delta vs R1:
// wsq-free 3-op scoring (absmax 0 in R6/R7) — removes the per-tile wsq load.
__global__ __launch_bounds__(512, 2) void pass1_kernel(
        const float* __restrict__ x, const ushort* __restrict__ wbf,
        float* __restrict__ idx_out,
        float* __restrict__ rowmin, int* __restrict__ flags,
        unsigned* __restrict__ flag_count, int* __restrict__ hard_flags,
        unsigned* __restrict__ hard_count, int* __restrict__ candcnt,
        int* __restrict__ cands) {
    __shared__ __align__(16) char smem[66560];        // max(2x32KB staging, 2x[128][65] f32)
    ushort* wt = reinterpret_cast<ushort*>(smem);

    const int t = threadIdx.x;
    const int lane = t & 63, ln31 = lane & 31, h = lane >> 5;
    const int wv = t >> 6;                            // 0..7
    const int rs = wv >> 1, cs = wv & 1;
    const int colL = cs * 32 + ln31;                  // 0..63 within col-block
    const int r0 = blockIdx.x * 128;

    // stage col-block 0 into buffer 0 (each wave: 4 x 1KB, identity copy)
    {
        const char* g = (const char*)wbf + (size_t)wv * 4096 + (size_t)lane * 16;
        char* l = (char*)wt + wv * 4096;
        #pragma unroll
        for (int i = 0; i < 4; ++i) ASYNC_COPY16(g + i * 1024, l + i * 1024);
    }

    // A fragments (this wave's 32 rows) -> registers
    const int arow = r0 + rs * 32 + ln31;
    const float4* xr = reinterpret_cast<const float4*>(x) + (size_t)arow * 64;
    bf16x8 afr[16];
    #pragma unroll
    for (int kk = 0; kk < 16; ++kk)
        afr[kk] = __builtin_bit_cast(bf16x8, pack8(xr[kk * 4 + h * 2], xr[kk * 4 + h * 2 + 1]));

    float b1[16], b2[16];
    #pragma unroll
    for (int r = 0; r < 16; ++r) { b1[r] = 3.4e38f; b2[r] = 3.4e38f; }

    const char* gW = (const char*)wbf + (size_t)wv * 4096 + (size_t)lane * 16;

    __syncthreads();                                  // block 0 staged (implicit vmcnt(0) drain)

    int cur = 0;
    for (int it = 0; it < 128; ++it) {
        // prefetch next col-block into the other buffer (overlaps with MFMA below)
        {
            const char* g = gW + (size_t)((it + 1) & 127) * 32768;
            char* l = (char*)wt + (cur ^ 1) * 32768 + wv * 4096;
            #pragma unroll
            for (int i = 0; i < 4; ++i) ASYNC_COPY16(g + i * 1024, l + i * 1024);
        }

        const ushort* bt = wt + cur * 16384;          // ushort units
        f32x16 acc = {0,0,0,0,0,0,0,0,0,0,0,0,0,0,0,0};
        #pragma unroll
        for (int kk = 0; kk < 16; ++kk) {             // conflict-free: 32 consecutive 16B/half-wave
            bf16x8 bf = *reinterpret_cast<const bf16x8*>(&bt[(kk * 2 + h) * 512 + colL * 8]);
            acc = __builtin_amdgcn_mfma_f32_32x32x16_bf16(afr[kk], bf, acc, 0, 0, 0);
        }

        const int kb = it * 64 + colL;
        #pragma unroll
        for (int r = 0; r < 16; ++r) {                // wsq-free 3-op min-track
            float p0 = __uint_as_float((__float_as_uint(acc[r]) & 0xFFFFE000u) | (unsigned)kb);
            b2[r] = __builtin_amdgcn_fmed3f(p0, b1[r], b2[r]);
            b1[r] = fminf(p0, b1[r]);
        }

        __syncthreads();                              // drains DMA; next buffer ready
        cur ^= 1;
    }

    // per-row slot arrays in LDS (stride 65 -> conflict-free column scans)
    float* sb1 = reinterpret_cast<float*>(smem);      // [128][65]
    float* sb2 = sb1 + 128 * 65;                      // [128][65]; total 66560 B exactly
    #pragma unroll
    for (int r = 0; r < 16; ++r) {
        int rl = rs * 32 + (r & 3) + 8 * (r >> 2) + 4 * h;   // C/D row mapping (verified)
        sb1[rl * 65 + colL] = b1[r];
        sb2[rl * 65 + colL] = b2[r];
    }
    __syncthreads();
    if (t < 128) {
        float B1 = 3.4e38f, B2 = 3.4e38f;
        for (int c = 0; c < 64; ++c) {
            float a1 = sb1[t * 65 + c], a2 = sb2[t * 65 + c];
            float nb2 = fminf(fmaxf(B1, a1), fminf(B2, a2));  // 2nd-smallest of {B1,B2,a1,a2}
            B1 = fminf(B1, a1);
            B2 = nb2;
        }
        int row = r0 + t;
        idx_out[row] = (float)(__float_as_uint(B1) & 0x1FFFu);
        rowmin[row]  = B1;
        int nc = 0;
        if (B2 - B1 <= M_FLAG) {
            unsigned pos = atomicAdd(flag_count, 1u);
            if (pos < N_ROWS) flags[pos] = row;
            // Lemma: dropped scores in slot L >= final b2(L). If b2(L) > T for all L,
            // {b1(L) <= T} is the complete candidate set; else row is "hard".
            float T = B1 + M_CAND;
            bool hard = false;
            for (int c = 0; c < 64; ++c) {
                float a1 = sb1[t * 65 + c];
                if (a1 <= T) {
                    if (nc < CAP) cands[row * CAP + nc] = (int)(__float_as_uint(a1) & 0x1FFFu);
                    ++nc;
                }
                if (sb2[t * 65 + c] <= T) hard = true;
            }
            if (nc > CAP) hard = true;
            if (hard) {
                nc = 0;                               // full sweep will refill
                unsigned hp = atomicAdd(hard_count, 1u);
                if (hp < N_ROWS) hard_flags[hp] = row;
            }
        }
        candcnt[row] = nc;
    }
}

// Full re-sweep for the rare "hard" rows (R1 structure; wsq-free thresholds, R7-executed).
__global__ __launch_bounds__(256, 2) void fixup_kernel(
        const float* __restrict__ x, const ushort* __restrict__ wbf,
        const float* __restrict__ rowmin,
        const int* __restrict__ hard_flags, const unsigned* __restrict__ hard_count,
        int* __restrict__ candcnt, int* __restrict__ cands) {
    __shared__ __align__(16) ushort wt[64 * 256];     // 32KB (one 64-col tile)
    __shared__ int   sh_rows[64];
    __shared__ float sh_thr[64];

    const int t = threadIdx.x;
    const int lane = t & 63, ln31 = lane & 31, h = lane >> 5;
    const int wv = t >> 6, rs = wv & 1, cs = wv >> 1;
    const int colL = cs * 32 + ln31;

    unsigned cu = hard_count[0];
    int cnt = cu > N_ROWS ? N_ROWS : (int)cu;
    int nunits = ((cnt + 63) >> 6) * 8;

    for (int u = blockIdx.x; u < nunits; u += 512) {
        int ksp  = u & 7;
        int base = (u >> 3) * 64;
        int nrows = cnt - base; if (nrows > 64) nrows = 64;

        __syncthreads();
        if (t < 64) {
            int valid = (t < nrows);
            int gr = hard_flags[base + (valid ? t : 0)];
            sh_rows[t] = gr;
            sh_thr[t]  = valid ? rowmin[gr] + M_CAND : -3.4e38f;
        }
        __syncthreads();

        int arow = sh_rows[rs * 32 + ln31];
        const float4* xr = reinterpret_cast<const float4*>(x) + (size_t)arow * 64;
        bf16x8 afr[16];
        #pragma unroll
        for (int kk = 0; kk < 16; ++kk)
            afr[kk] = __builtin_bit_cast(bf16x8, pack8(xr[kk * 4 + h * 2], xr[kk * 4 + h * 2 + 1]));
        float thr_r[16];
        int   rl_r[16];
        #pragma unroll
        for (int r = 0; r < 16; ++r) {
            rl_r[r]  = rs * 32 + (r & 3) + 8 * (r >> 2) + 4 * h;
            thr_r[r] = sh_thr[rl_r[r]];
        }

        for (int tb = 0; tb < 16; ++tb) {
            int blk = ksp * 16 + tb;                  // 64-col block index
            __syncthreads();                          // previous tile fully consumed
            {
                const char* g = (const char*)wbf + (size_t)blk * 32768
                              + (size_t)wv * 8192 + (size_t)lane * 16;
                char* l = (char*)wt + wv * 8192;
                #pragma unroll
                for (int i = 0; i < 8; ++i) ASYNC_COPY16(g + i * 1024, l + i * 1024);
            }
            __syncthreads();                          // drains vmcnt before reads

            int kcol = blk * 64 + colL;
            f32x16 acc = {0,0,0,0,0,0,0,0,0,0,0,0,0,0,0,0};
            #pragma unroll
            for (int kk = 0; kk < 16; ++kk) {
                bf16x8 bf = *reinterpret_cast<const bf16x8*>(&wt[(size_t)(kk * 2 + h) * 512 + colL * 8]);
                acc = __builtin_amdgcn_mfma_f32_32x32x16_bf16(afr[kk], bf, acc, 0, 0, 0);
            }
            #pragma unroll
            for (int r = 0; r < 16; ++r) {
                float s0 = acc[r];                    // wsq-free, consistent with rowmin
                if (s0 <= thr_r[r]) {
                    int grow = sh_rows[rl_r[r]];
                    int pos = atomicAdd(&candcnt[grow], 1);
                    if (pos < CAP) cands[grow * CAP + pos] = kcol;
                }
            }
        }
    }
}

// np-exact rescore (R1-verbatim): q = fl32(fl32(Xsq - 2*fl32(dot64)) + Wsq), lowest-index ties.
__global__ __launch_bounds__(256) void rescore_kernel(
        const float* __restrict__ x, const float* __restrict__ w,
        const float* __restrict__ wsq,
        const int* __restrict__ flags, const unsigned* __restrict__ flag_count,
        const int* __restrict__ candcnt, const int* __restrict__ cands,
        float* __restrict__ idx_out) {
    int wid  = (blockIdx.x * 256 + threadIdx.x) >> 6;
    int lane = threadIdx.x & 63;
    unsigned cu = flag_count[0];
    int cnt = (cu > N_ROWS) ? N_ROWS : (int)cu;

    for (int fi = wid; fi < cnt; fi += 1024) {
        int row = flags[fi];
        float4 xv = reinterpret_cast<const float4*>(x)[(size_t)row * 64 + lane];
        double xs = (double)xv.x * xv.x + (double)xv.y * xv.y
                  + (double)xv.z * xv.z + (double)xv.w * xv.w;
        #pragma unroll
        for (int off = 1; off < 64; off <<= 1) xs += __shfl_xor(xs, off, 64);
        float Xs = (float)xs;
        int nc = candcnt[row]; if (nc > CAP) nc = CAP;
        float bq = 3.4e38f; int bk = -1;
        for (int c = 0; c < nc; ++c) {
            int k = cands[row * CAP + c];
            float4 wv = reinterpret_cast<const float4*>(w)[(size_t)k * 64 + lane];
            double d = (double)xv.x * wv.x + (double)xv.y * wv.y
                     + (double)xv.z * wv.z + (double)xv.w * wv.w;
            #pragma unroll
            for (int off = 1; off < 64; off <<= 1) d += __shfl_xor(d, off, 64);
            float XW = (float)d;
            float t3 = fmaf(-2.0f, XW, Xs);
            float qv = t3 + wsq[k];
            if (qv < bq || (qv == bq && k < bk) || bk < 0) { bq = qv; bk = k; }
        }
        if (lane == 0 && bk >= 0) idx_out[row] = (float)bk;
    }
}

__global__ __launch_bounds__(256) void gather_loss_kernel(
        const float* __restrict__ x, const float* __restrict__ w,
        const float* __restrict__ idx_f, float* __restrict__ out_q,
        float* __restrict__ accum) {
    const int nf4 = Q_ELEMS / 4;
    float lsum = 0.0f;
    for (int e = blockIdx.x * blockDim.x + threadIdx.x; e < nf4;
         e += gridDim.x * blockDim.x) {
        int row = e >> 6, d4 = e & 63;
        int k = (int)idx_f[row];
        float4 xv = reinterpret_cast<const float4*>(x)[e];
        float4 qv = reinterpret_cast<const float4*>(w)[(size_t)k * 64 + d4];
        float4 ov;
        ov.x = xv.x + (qv.x - xv.x);
        ov.y = xv.y + (qv.y - xv.y);
        ov.z = xv.z + (qv.z - xv.z);
        ov.w = xv.w + (qv.w - xv.w);
        reinterpret_cast<float4*>(out_q)[e] = ov;
        float dx = xv.x - qv.x, dy = xv.y - qv.y, dz = xv.z - qv.z, dw = xv.w - qv.w;
        lsum += dx * dx + dy * dy + dz * dz + dw * dw;
    }
    #pragma unroll
    for (int off = 32; off > 0; off >>= 1) lsum += __shfl_down(lsum, off, 64);
    __shared__ float ssum[4];
    if ((threadIdx.x & 63) == 0) ssum[threadIdx.x >> 6] = lsum;
    __syncthreads();
    if (threadIdx.x == 0)
        atomicAdd(accum, ssum[0] + ssum[1] + ssum[2] + ssum[3]);
}

__global__ void finalize_kernel(const float* __restrict__ accum,
                                float* __restrict__ out_tail) {
    float mse = accum[0] / (float)Q_ELEMS;
    float commit = 0.25f * mse;
    out_tail[0] = commit;
    out_tail[1] = mse;
    out_tail[2] = commit + mse;
}

extern "C" void kernel_launch(void* const* d_in, const int* in_sizes, int n_in,
                              void* d_out, int out_size, void* d_ws, size_t ws_size,
                              hipStream_t stream) {
    const float* x = (const float*)d_in[0];
    const float* w = (const float*)d_in[1];
    float* out = (float*)d_out;

    char* ws = (char*)d_ws;
    float*    Wsq        = (float*)ws;
    float*    Rmin       = (float*)(ws + 163840);
    float*    accum      = (float*)(ws + 294912);
    unsigned* flag_count = (unsigned*)(ws + 294916);
    unsigned* hard_count = (unsigned*)(ws + 294920);
    int*      flags      = (int*)(ws + 294924);
    int*      hard_flags = (int*)(ws + 425996);
    int*      candcnt    = (int*)(ws + 557068);
    int*      cands      = (int*)(ws + 688140);
    ushort*   Wbf        = (ushort*)(ws + 2785296);

    hipMemsetAsync(ws + 294912, 0, 12, stream);   // accum + flag_count + hard_count
    wsq_wbf_kernel<<<K_CB / 64, 256, 0, stream>>>(w, Wsq, Wbf);
    pass1_kernel<<<N_ROWS / 128, 512, 0, stream>>>(x, Wbf, out + Q_ELEMS,
                                                   Rmin, flags, flag_count,
                                                   hard_flags, hard_count,
                                                   candcnt, cands);
    fixup_kernel<<<512, 256, 0, stream>>>(x, Wbf, Rmin, hard_flags, hard_count,
                                          candcnt, cands);
    rescore_kernel<<<256, 256, 0, stream>>>(x, w, Wsq, flags, flag_count,
                                            candcnt, cands, out + Q_ELEMS);
    gather_loss_kernel<<<8192, 256, 0, stream>>>(x, w, out + Q_ELEMS, out, accum);
    finalize_kernel<<<1, 1, 0, stream>>>(accum, out + Q_ELEMS + N_ROWS);
}